// Round 6
// baseline (1312.076 us; speedup 1.0000x reference)
//
#include <hip/hip_runtime.h>

#define HW 1024
#define NIMG 32
#define IMGPX ((size_t)HW * HW)
#define NELEM (NIMG * IMGPX)

typedef float f2 __attribute__((ext_vector_type(2)));

// region/tile geometry: compute region 128x128 per block, ring 6 -> out 116x116
#define RING 6
#define TOUT 116
#define NB 9          // ceil(1024/116)
#define LROWS 130     // LDS rows: region rows -1..128
#define LSTR 136      // words/LDS row; region col c(0..127)->word c; col -1 -> word 130; col 128 -> word 131

// ---- float <-> order-preserving unsigned (for atomic min/max) ----
__device__ __forceinline__ unsigned f2su(float f) {
    unsigned u = __float_as_uint(f);
    return (u & 0x80000000u) ? ~u : (u | 0x80000000u);
}
__device__ __forceinline__ float s2f(unsigned u) {
    return __uint_as_float((u & 0x80000000u) ? (u & 0x7fffffffu) : ~u);
}

__global__ void mm_init(unsigned* mm) {
    mm[0] = 0xFFFFFFFFu;
    mm[1] = 0u;
}

__global__ __launch_bounds__(256) void mm_reduce(const float4* __restrict__ x,
                                                 unsigned* mm, int n4) {
    const int tid = threadIdx.x;
    int gid = blockIdx.x * blockDim.x + tid;
    const int stride = gridDim.x * blockDim.x;
    float vmin = 3.4e38f, vmax = -3.4e38f;
    for (int i = gid; i < n4; i += stride) {
        float4 v = x[i];
        vmin = fminf(vmin, fminf(fminf(v.x, v.y), fminf(v.z, v.w)));
        vmax = fmaxf(vmax, fmaxf(fmaxf(v.x, v.y), fmaxf(v.z, v.w)));
    }
    __shared__ float smin[256];
    __shared__ float smax[256];
    smin[tid] = vmin; smax[tid] = vmax;
    __syncthreads();
    for (int s = 128; s > 0; s >>= 1) {
        if (tid < s) {
            smin[tid] = fminf(smin[tid], smin[tid + s]);
            smax[tid] = fmaxf(smax[tid], smax[tid + s]);
        }
        __syncthreads();
    }
    if (tid == 0) {
        atomicMin(&mm[0], f2su(smin[0]));
        atomicMax(&mm[1], f2su(smax[0]));
    }
}

struct RowW { f2 P[4]; float L, R; };

// 512 threads: tx 0..15 owns 8 cols (as 4 f2 pairs), tyg 0..31 owns 4 rows.
// State lives in registers; LDS exchanges only group-boundary rows per step.
template <int FIRST, int LAST>
__global__ __launch_bounds__(512) void fused_k(
    const float* __restrict__ x, const float* __restrict__ sin_,
    float* __restrict__ sout, const unsigned* __restrict__ mm,
    const float* __restrict__ wAp, const float* __restrict__ wBp,
    const float* __restrict__ biasp) {
#pragma clang fp contract(off)
    __shared__ float sb[LROWS * LSTR];
    const int tid = threadIdx.x;
    const int tx = tid & 15;
    const int tyg = tid >> 4;
    const int lane = tid & 63;
    const int laneL = (lane + 63) & 63;
    const int laneR = (lane + 1) & 63;
    const int r0 = tyg << 2;
    const int c0 = tx << 3;
    const int ox = (int)blockIdx.x * TOUT - RING;
    const int oy = (int)blockIdx.y * TOUT - RING;
    const size_t img = (size_t)blockIdx.z * IMGPX;
    const bool edgeX = (blockIdx.x == 0) | (blockIdx.x == NB - 1);

    const float xmin = s2f(mm[0]);
    const float xmax = s2f(mm[1]);
    const float scale = 2.0f / (xmax - xmin);
    const float b = biasp[0];

    // ---- phase 1: xn full tile into LDS (incl. halo col words 130/131) ----
    for (int k = tid; k < LROWS * LROWS; k += 512) {
        const int ri = k / LROWS;           // 0..129  (region row ri-1)
        const int ci = k - ri * LROWS;      // 0..129  (region col ci-1)
        const int cc = ci - 1;
        const int w = (cc == -1) ? 130 : ((cc == 128) ? 131 : cc);
        const int gr = oy + ri - 1;
        const int gc = ox + cc;
        float v = 0.0f;
        if (gr >= 0 && gr < HW && gc >= 0 && gc < HW)
            v = (x[img + (size_t)gr * HW + gc] - xmin) * scale - 1.0f;
        sb[ri * LSTR + w] = v;
    }
    __syncthreads();

    // row loader from LDS (aligned b128 x2 + 2 shfl + 2 broadcast)
    auto ldRow = [&](int rreg) -> RowW {
        RowW o;
        const int base = (rreg + 1) * LSTR;
        const float4 q0 = *reinterpret_cast<const float4*>(&sb[base + c0]);
        const float4 q1 = *reinterpret_cast<const float4*>(&sb[base + c0 + 4]);
        o.P[0] = f2{q0.x, q0.y}; o.P[1] = f2{q0.z, q0.w};
        o.P[2] = f2{q1.x, q1.y}; o.P[3] = f2{q1.z, q1.w};
        const float fromL = __shfl(q1.w, laneL);
        const float fromR = __shfl(q0.x, laneR);
        o.L = (tx == 0) ? sb[base + 130] : fromL;
        o.R = (tx == 15) ? sb[base + 131] : fromR;
        return o;
    };

    float cf[9];
    // 9-term sequential row-major conv for pixel pair p (exact numpy order per element)
    auto conv9 = [&](const RowW& A, const RowW& B, const RowW& C, int p) -> f2 {
#pragma clang fp contract(off)
        f2 acc = f2{0.0f, 0.0f};
        f2 tl, tr;
        tl = f2{(p == 0) ? A.L : A.P[p - 1].y, A.P[p].x};
        tr = f2{A.P[p].y, (p == 3) ? A.R : A.P[p + 1].x};
        acc = acc + f2{cf[0], cf[0]} * tl;
        acc = acc + f2{cf[1], cf[1]} * A.P[p];
        acc = acc + f2{cf[2], cf[2]} * tr;
        tl = f2{(p == 0) ? B.L : B.P[p - 1].y, B.P[p].x};
        tr = f2{B.P[p].y, (p == 3) ? B.R : B.P[p + 1].x};
        acc = acc + f2{cf[3], cf[3]} * tl;
        acc = acc + f2{cf[4], cf[4]} * B.P[p];
        acc = acc + f2{cf[5], cf[5]} * tr;
        tl = f2{(p == 0) ? C.L : C.P[p - 1].y, C.P[p].x};
        tr = f2{C.P[p].y, (p == 3) ? C.R : C.P[p + 1].x};
        acc = acc + f2{cf[6], cf[6]} * tl;
        acc = acc + f2{cf[7], cf[7]} * C.P[p];
        acc = acc + f2{cf[8], cf[8]} * tr;
        return acc;
    };

    // ---- phase 2: BU = conv(xn, B) into registers (time-invariant) ----
#pragma unroll
    for (int i = 0; i < 9; ++i) cf[i] = wBp[i];
    f2 bu[4][4];
    {
        RowW ra = ldRow(r0 - 1), rb = ldRow(r0);
#pragma unroll
        for (int i = 0; i < 4; ++i) {
            RowW rc = ldRow(r0 + i + 1);
#pragma unroll
            for (int p = 0; p < 4; ++p) bu[i][p] = conv9(ra, rb, rc, p);
            ra = rb; rb = rc;
        }
    }
    __syncthreads();

    // ---- phase 3: stage s into registers + LDS halo/boundary slots ----
    f2 res[4][4];
    float hL[4], hR[4];
    if (FIRST) {
#pragma unroll
        for (int i = 0; i < 4; ++i) {
            hL[i] = 0.0f; hR[i] = 0.0f;
#pragma unroll
            for (int p = 0; p < 4; ++p) res[i][p] = f2{0.0f, 0.0f};
        }
        for (int k = tid; k < 516; k += 512) {
            int rr, cc;
            if (k < 260) { rr = (k < 130) ? -1 : 128; cc = (k % 130) - 1; }
            else { const int kk = k - 260; rr = kk >> 1; cc = (kk & 1) ? 128 : -1; }
            const int w = (cc == -1) ? 130 : ((cc == 128) ? 131 : cc);
            sb[(rr + 1) * LSTR + w] = 0.0f;
        }
    } else {
        for (int k = tid; k < 516; k += 512) {
            int rr, cc;
            if (k < 260) { rr = (k < 130) ? -1 : 128; cc = (k % 130) - 1; }
            else { const int kk = k - 260; rr = kk >> 1; cc = (kk & 1) ? 128 : -1; }
            const int w = (cc == -1) ? 130 : ((cc == 128) ? 131 : cc);
            const int gr = oy + rr, gc = ox + cc;
            float v = 0.0f;
            if (gr >= 0 && gr < HW && gc >= 0 && gc < HW) v = sin_[img + (size_t)gr * HW + gc];
            sb[(rr + 1) * LSTR + w] = v;
        }
#pragma unroll
        for (int i = 0; i < 4; ++i) {
            const int gr = oy + r0 + i;
            const bool rin = (gr >= 0) & (gr < HW);
            if (!edgeX && rin) {
                const float2* src = reinterpret_cast<const float2*>(&sin_[img + (size_t)gr * HW + ox + c0]);
#pragma unroll
                for (int p = 0; p < 4; ++p) { const float2 t = src[p]; res[i][p] = f2{t.x, t.y}; }
            } else {
#pragma unroll
                for (int cl = 0; cl < 8; ++cl) {
                    const int gc = ox + c0 + cl;
                    float v = 0.0f;
                    if (rin && gc >= 0 && gc < HW) v = sin_[img + (size_t)gr * HW + gc];
                    res[i][cl >> 1][cl & 1] = v;
                }
            }
            const int gcl = ox - 1, gcr = ox + 128;
            hL[i] = (rin && gcl >= 0) ? sin_[img + (size_t)gr * HW + gcl] : 0.0f;
            hR[i] = (rin && gcr < HW) ? sin_[img + (size_t)gr * HW + gcr] : 0.0f;
        }
    }

    auto wrRow = [&](int i) {
        const int base = (r0 + i + 1) * LSTR + c0;
        *reinterpret_cast<float4*>(&sb[base]) =
            make_float4(res[i][0].x, res[i][0].y, res[i][1].x, res[i][1].y);
        *reinterpret_cast<float4*>(&sb[base + 4]) =
            make_float4(res[i][2].x, res[i][2].y, res[i][3].x, res[i][3].y);
    };
    wrRow(0); wrRow(3);
    __syncthreads();

    // ---- phase 4: 7 fused steps, state in registers ----
#pragma unroll
    for (int i = 0; i < 9; ++i) cf[i] = wAp[i];
    const f2 b2 = f2{b, b};
    f2 mR2[4], mC2[4];
#pragma unroll
    for (int i = 0; i < 4; ++i) {
        const int g = oy + r0 + i;
        const float m = (g >= 0 && g < HW) ? 1.0f : 0.0f;
        mR2[i] = f2{m, m};
    }
#pragma unroll
    for (int p = 0; p < 4; ++p) {
        const int g0 = ox + c0 + 2 * p, g1 = g0 + 1;
        mC2[p] = f2{(g0 >= 0 && g0 < HW) ? 1.0f : 0.0f,
                    (g1 >= 0 && g1 < HW) ? 1.0f : 0.0f};
    }

#pragma unroll 1
    for (int t = 0; t < 7; ++t) {
        const RowW m1 = ldRow(r0 - 1);
        const RowW p4 = ldRow(r0 + 4);
        __syncthreads();  // all reads of old boundary rows complete

        RowW o[4];
#pragma unroll
        for (int i = 0; i < 4; ++i) {
            o[i].P[0] = res[i][0]; o[i].P[1] = res[i][1];
            o[i].P[2] = res[i][2]; o[i].P[3] = res[i][3];
            const float fromL = __shfl(res[i][3].y, laneL);
            const float fromR = __shfl(res[i][0].x, laneR);
            o[i].L = (tx == 0) ? hL[i] : fromL;
            o[i].R = (tx == 15) ? hR[i] : fromR;
        }
        f2 nw[4][4];
#pragma unroll
        for (int i = 0; i < 4; ++i) {
            const RowW& A = (i == 0) ? m1 : o[i - 1];
            const RowW& B = o[i];
            const RowW& C = (i == 3) ? p4 : o[i + 1];
#pragma unroll
            for (int p = 0; p < 4; ++p) {
                f2 v = conv9(A, B, C, p);
                v = (v + b2) + bu[i][p];
                v = __builtin_elementwise_max(v, f2{-1.0f, -1.0f});
                v = __builtin_elementwise_min(v, f2{1.0f, 1.0f});
                v = v * mR2[i];
                v = v * mC2[p];
                nw[i][p] = v;
            }
        }
#pragma unroll
        for (int i = 0; i < 4; ++i)
#pragma unroll
            for (int p = 0; p < 4; ++p) res[i][p] = nw[i][p];
        wrRow(0); wrRow(3);
        __syncthreads();  // new boundary rows visible
    }

    // ---- phase 5: store inner 116x116 tile ----
#pragma unroll
    for (int i = 0; i < 4; ++i) {
        const int r = r0 + i;
        if (r < RING || r >= RING + TOUT) continue;
        const int gr = oy + r;
        if (gr >= HW) continue;  // gr >= 0 guaranteed (oy >= -6, r >= 6)
        if (!edgeX && tx >= 1 && tx <= 14) {
            float2* dst = reinterpret_cast<float2*>(&sout[img + (size_t)gr * HW + ox + c0]);
#pragma unroll
            for (int p = 0; p < 4; ++p) {
                f2 v = res[i][p];
                if (LAST) v = (v + f2{1.0f, 1.0f}) * f2{0.5f, 0.5f};
                dst[p] = make_float2(v.x, v.y);
            }
        } else {
#pragma unroll
            for (int cl = 0; cl < 8; ++cl) {
                const int c = c0 + cl;
                if (c < RING || c >= RING + TOUT) continue;
                const int gc = ox + c;
                if (gc >= HW) continue;  // gc >= 0 since c >= 6
                float v = res[i][cl >> 1][cl & 1];
                if (LAST) v = (v + 1.0f) * 0.5f;
                sout[img + (size_t)gr * HW + gc] = v;
            }
        }
    }
}

extern "C" void kernel_launch(void* const* d_in, const int* in_sizes, int n_in,
                              void* d_out, int out_size, void* d_ws, size_t ws_size,
                              hipStream_t stream) {
    const float* x = (const float*)d_in[0];
    const float* wA = (const float*)d_in[1];
    const float* wB = (const float*)d_in[2];
    const float* bias = (const float*)d_in[3];
    float* out = (float*)d_out;
    unsigned* mm = (unsigned*)d_ws;
    float* pong = (float*)((char*)d_ws + 1024);  // 128 MiB f32 buffer

    mm_init<<<1, 1, 0, stream>>>(mm);
    mm_reduce<<<2048, 256, 0, stream>>>((const float4*)x, mm, (int)(NELEM / 4));

    dim3 grid(NB, NB, NIMG);
    // steps 1-7: zeros -> out (scratch); 8-14: out -> pong; 15-21: pong -> out
    fused_k<1, 0><<<grid, 512, 0, stream>>>(x, nullptr, out, mm, wA, wB, bias);
    fused_k<0, 0><<<grid, 512, 0, stream>>>(x, out, pong, mm, wA, wB, bias);
    fused_k<0, 1><<<grid, 512, 0, stream>>>(x, pong, out, mm, wA, wB, bias);
}